// Round 9
// baseline (28852.185 us; speedup 1.0000x reference)
//
#include <hip/hip_runtime.h>
#include <math.h>
#include <stdint.h>

// ---- problem constants ----
static const int NS = 4096;    // samples
static const int MF = 1000;    // features
static const int NCOMP = 50;   // principal components

// out layout: pseudotime [4096] | transition [4096*4096] | pca [4096*50]
#define TR_OFF  ((size_t)4096)
#define PCA_OFF ((size_t)4096 + (size_t)4096*4096)

// ---------------- column mean ----------------
__global__ void k_colsum(const float* __restrict__ x, float* __restrict__ part){
  int b = blockIdx.x, tid = threadIdx.x;
  float a0=0,a1=0,a2=0,a3=0;
  for (int r=b*64; r<b*64+64; r++){
    const float* row = x + (size_t)r*MF;
    if (tid      < MF) a0 += row[tid];
    if (tid+256  < MF) a1 += row[tid+256];
    if (tid+512  < MF) a2 += row[tid+512];
    if (tid+768  < MF) a3 += row[tid+768];
  }
  if (tid      < MF) part[b*MF+tid]     = a0;
  if (tid+256  < MF) part[b*MF+tid+256] = a1;
  if (tid+512  < MF) part[b*MF+tid+512] = a2;
  if (tid+768  < MF) part[b*MF+tid+768] = a3;
}

__global__ void k_colmean(const float* __restrict__ part, float* __restrict__ mean){
  int c = blockIdx.x*256 + threadIdx.x;
  if (c < MF){ float s=0; for (int b=0;b<64;b++) s += part[b*MF+c]; mean[c] = s/4096.0f; }
}

// ---------------- cov = (x-mean)^T (x-mean) / (n-1), fp64 out ----------------
__global__ void k_cov(const float* __restrict__ x, const float* __restrict__ mean,
                      double* __restrict__ Ah){
  __shared__ float As[32][65];
  __shared__ float Bs[32][65];
  int i0 = blockIdx.y*64, j0 = blockIdx.x*64;
  int tx = threadIdx.x, ty = threadIdx.y;
  int tid = ty*16+tx;
  double acc[4][4];
  #pragma unroll
  for (int u=0;u<4;u++)
    #pragma unroll
    for (int v=0;v<4;v++) acc[u][v]=0.0;
  for (int k0=0;k0<4096;k0+=32){
    for (int t=tid;t<32*64;t+=256){
      int kk=t>>6, ii=t&63;
      int gi=i0+ii, gj=j0+ii;
      As[kk][ii] = (gi<MF) ? (x[(size_t)(k0+kk)*MF+gi]-mean[gi]) : 0.f;
      Bs[kk][ii] = (gj<MF) ? (x[(size_t)(k0+kk)*MF+gj]-mean[gj]) : 0.f;
    }
    __syncthreads();
    for (int kk=0;kk<32;kk++){
      float a[4], b[4];
      #pragma unroll
      for (int u=0;u<4;u++){ a[u]=As[kk][ty*4+u]; b[u]=Bs[kk][tx*4+u]; }
      #pragma unroll
      for (int u=0;u<4;u++)
        #pragma unroll
        for (int v=0;v<4;v++) acc[u][v] += (double)a[u]*(double)b[v];
    }
    __syncthreads();
  }
  #pragma unroll
  for (int u=0;u<4;u++)
    #pragma unroll
    for (int v=0;v<4;v++){
      int gi=i0+ty*4+u, gj=j0+tx*4+v;
      if (gi<MF && gj<MF) Ah[(size_t)gi*MF+gj] = acc[u][v]*(1.0/4095.0);
    }
}

__device__ __forceinline__ unsigned wang(unsigned s){
  s=(s^61u)^(s>>16); s*=9u; s^=s>>4; s*=0x27d4eb2du; s^=s>>15; return s;
}

// ======== fp64 Householder tridiagonalization (dsytd2 'L') ========
__global__ void k_hh_reflect(const double* __restrict__ Ah, double* __restrict__ Vh,
                             double* __restrict__ tauv, double* __restrict__ betaH, int k){
  __shared__ double red[256];
  __shared__ double sb[1];
  int m = 999 - k;
  int tid = threadIdx.x;
  double alpha = Ah[(size_t)(k+1)*MF + k];
  double a = 0;
  for (int t = 1 + tid; t < m; t += 256){
    double xv = Ah[(size_t)(k+1+t)*MF + k];
    a += xv*xv;
  }
  red[tid]=a; __syncthreads();
  for (int off=128; off; off>>=1){ if (tid<off) red[tid]+=red[tid+off]; __syncthreads(); }
  if (tid==0){
    double xn2 = red[0];
    double beta, tau, scl;
    if (xn2 == 0.0){ beta = alpha; tau = 0.0; scl = 0.0; }
    else {
      double nrm = sqrt(alpha*alpha + xn2);
      beta = (alpha >= 0.0) ? -nrm : nrm;   // dlarfg: beta = -sign(alpha)*norm
      tau  = (beta - alpha)/beta;
      scl  = 1.0/(alpha - beta);
    }
    betaH[k]=beta; tauv[k]=tau;
    sb[0]=scl;
    Vh[(size_t)k*MF + (k+1)] = 1.0;
  }
  __syncthreads();
  double scl = sb[0];
  for (int t = 1 + tid; t < m; t += 256){
    double xv = Ah[(size_t)(k+1+t)*MF + k];
    Vh[(size_t)k*MF + (k+1+t)] = xv*scl;
  }
}

__global__ void k_hh_symv(const double* __restrict__ Ah, const double* __restrict__ Vh,
                          double* __restrict__ w1, int k){
  __shared__ double red[256];
  int m = 999 - k;
  const double* v = Vh + (size_t)k*MF;
  for (int rr = blockIdx.x; rr < m; rr += gridDim.x){
    int r = k+1+rr;
    const double* row = Ah + (size_t)r*MF;
    double a=0;
    for (int c = k+1+threadIdx.x; c < MF; c += 256) a += row[c]*v[c];
    red[threadIdx.x]=a; __syncthreads();
    for (int off=128; off; off>>=1){
      if (threadIdx.x<off) red[threadIdx.x]+=red[threadIdx.x+off];
      __syncthreads();
    }
    if (threadIdx.x==0) w1[r]=red[0];
    __syncthreads();
  }
}

__global__ void k_hh_rank2(double* __restrict__ Ah, const double* __restrict__ Vh,
                           const double* __restrict__ w1, const double* __restrict__ tauv,
                           int k){
  __shared__ double red[256];
  int m = 999 - k;
  const double* v = Vh + (size_t)k*MF;
  double a=0;
  for (int j=k+1+threadIdx.x; j<1000; j+=256) a += v[j]*w1[j];
  red[threadIdx.x]=a; __syncthreads();
  for (int off=128; off; off>>=1){
    if (threadIdx.x<off) red[threadIdx.x]+=red[threadIdx.x+off];
    __syncthreads();
  }
  double tau = tauv[k];
  double hts = 0.5*tau*tau*red[0];
  for (int rr = blockIdx.x; rr < m; rr += gridDim.x){
    int r = k+1+rr;
    double vr = v[r];
    double wr = tau*w1[r] - hts*vr;
    double* row = Ah + (size_t)r*MF;
    for (int cc = threadIdx.x; cc < m; cc += 256){
      int c = k+1+cc;
      double wc = tau*w1[c] - hts*v[c];
      row[c] -= vr*wc + wr*v[c];
    }
  }
}

__global__ void k_hh_extract(const double* __restrict__ Ah, double* __restrict__ alphaH,
                             double* __restrict__ betaH){
  int t = blockIdx.x*256 + threadIdx.x;
  if (t < MF) alphaH[t] = Ah[(size_t)t*MF+t];
  if (t == 0) betaH[998] = Ah[(size_t)999*MF+998];
}

// ---- Sturm bisection: top-50 eigenvalues of T ----
__global__ void k_bisect(const double* __restrict__ alphaT, const double* __restrict__ betaT,
                         double* __restrict__ lamT){
  int i = blockIdx.x*blockDim.x + threadIdx.x;
  if (i >= NCOMP) return;
  double lo=1e300, hi=-1e300;
  for (int k=0;k<1000;k++){
    double bl = (k>0)? fabs(betaT[k-1]) : 0.0;
    double br = (k<999)? fabs(betaT[k]) : 0.0;
    double a = alphaT[k];
    lo = fmin(lo, a-bl-br);
    hi = fmax(hi, a+bl+br);
  }
  int target = 999 - i;
  for (int it=0; it<90; it++){
    double mid = 0.5*(lo+hi);
    int cnt=0;
    double d = alphaT[0]-mid;
    if (d<0.0) cnt++;
    for (int k=1;k<1000;k++){
      double b = betaT[k-1];
      double den = d;
      if (fabs(den) < 1e-300) den = (den<0.0)?-1e-300:1e-300;
      d = alphaT[k]-mid - b*b/den;
      if (d<0.0) cnt++;
    }
    if (cnt > target) hi = mid; else lo = mid;
  }
  lamT[i] = 0.5*(lo+hi);
}

// ---- serial pivoted tridiagonal solve (LAPACK dgtsv replica), thread-0 only ----
__device__ void gtsv_serial(int m, double* dl, double* dd, double* du, double* x){
  for (int r=0;r<m-1;r++){
    if (fabs(dd[r]) >= fabs(dl[r])){
      if (dd[r] != 0.0){
        double fact = dl[r]/dd[r];
        dd[r+1] -= fact*du[r];
        x[r+1]  -= fact*x[r];
      }
      if (r < m-2) dl[r] = 0.0;
    } else {
      double fact = dd[r]/dl[r];
      dd[r] = dl[r];
      double tdd = dd[r+1];
      dd[r+1] = du[r] - fact*tdd;
      if (r < m-2){
        double tdu = du[r+1];
        dl[r] = tdu;
        du[r+1] = -fact*tdu;
      }
      du[r] = tdd;
      double t2 = x[r]; x[r] = x[r+1]; x[r+1] = t2 - fact*x[r+1];
    }
  }
  x[m-1] /= dd[m-1];
  if (m >= 2) x[m-2] = (x[m-2] - du[m-2]*x[m-1])/dd[m-2];
  for (int r=m-3;r>=0;r--)
    x[r] = (x[r] - du[r]*x[r+1] - dl[r]*x[r+2])/dd[r];
}

// ---- inverse iteration on full T: fp64 eigenvector + refined lambda ----
__global__ void __launch_bounds__(256) k_inviter(const double* __restrict__ alphaH,
                                                 const double* __restrict__ betaH,
                                                 const double* __restrict__ lamT,
                                                 double* __restrict__ V50,
                                                 double* __restrict__ lamR){
  __shared__ double v[1000], xx[1000], dd[1000], du[1000], dl[1000];
  __shared__ double red[256];
  int i = blockIdx.x, tid = threadIdx.x;
  double lam = lamT[i];
  for (int t=tid;t<1000;t+=256){
    unsigned h = wang((unsigned)(i*1000+t)*2654435761u + 777u);
    v[t] = (double)(h & 0xffffffu)/8388608.0 - 1.0;
  }
  __syncthreads();
  for (int it=0; it<3; it++){
    for (int t=tid;t<1000;t+=256){
      dd[t] = alphaH[t]-lam;
      if (t<999){ du[t]=betaH[t]; dl[t]=betaH[t]; }
      xx[t] = v[t];
    }
    __syncthreads();
    if (tid==0) gtsv_serial(1000, dl, dd, du, xx);
    __syncthreads();
    double a=0; for (int t=tid;t<1000;t+=256) a += xx[t]*xx[t];
    red[tid]=a; __syncthreads();
    for (int off=128;off;off>>=1){ if(tid<off) red[tid]+=red[tid+off]; __syncthreads(); }
    double inv = 1.0/sqrt(red[0]);
    __syncthreads();
    for (int t=tid;t<1000;t+=256) v[t]=xx[t]*inv;
    __syncthreads();
  }
  double a=0;
  for (int t=tid;t<1000;t+=256){
    double s = alphaH[t]*v[t];
    if (t>0)   s += betaH[t-1]*v[t-1];
    if (t<999) s += betaH[t]*v[t+1];
    a += v[t]*s;
  }
  red[tid]=a; __syncthreads();
  for (int off=128;off;off>>=1){ if(tid<off) red[tid]+=red[tid+off]; __syncthreads(); }
  if (tid==0) lamR[i]=red[0];
  for (int t=tid;t<1000;t+=256) V50[(size_t)i*1000+t]=v[t];
}

// ---- LAPACK D&C sign replication: descend merge tree to last-active level,
//      apply exact secular orientation invariant v[c-1] < 0 / sign(v[c]) = -sign(E) ----
__global__ void __launch_bounds__(256) k_sign(const double* __restrict__ alphaH,
                                              const double* __restrict__ betaH,
                                              const double* __restrict__ V50,
                                              const double* __restrict__ lamR,
                                              float* __restrict__ sgnv){
  __shared__ double v[1000], xx[1000], dd[1000], du[1000], dl[1000];
  __shared__ double red[256];
  __shared__ double lam_s;
  __shared__ int ab[2];
  __shared__ float sig;
  int i = blockIdx.x, tid = threadIdx.x;
  for (int t=tid;t<1000;t+=256) v[t]=V50[(size_t)i*1000+t];
  if (tid==0){ lam_s=lamR[i]; ab[0]=0; ab[1]=1000; sig=1.f; }
  __syncthreads();
  while (true){
    int a=ab[0], b=ab[1];
    if (b-a <= 25) break;   // leaf (ssteqr territory): fallback sig=+1
    int c = a + (b-a)/2;    // slaed0 cutpoint
    // half masses
    double m1=0,m2=0;
    for (int t=a+tid;t<b;t+=256){ double q=v[t]*v[t]; if (t<c) m1+=q; else m2+=q; }
    red[tid]=m1; __syncthreads();
    for (int off=128;off;off>>=1){ if(tid<off) red[tid]+=red[tid+off]; __syncthreads(); }
    double M1=red[0]; __syncthreads();
    red[tid]=m2; __syncthreads();
    for (int off=128;off;off>>=1){ if(tid<off) red[tid]+=red[tid+off]; __syncthreads(); }
    double M2=red[0]; __syncthreads();
    double tot=M1+M2;
    if (fmin(M1,M2) <= 1e-10*tot){
      // deflated at this level: descend into dominant half, re-refine eigenpair there
      if (tid==0){ if (M1>=M2) ab[1]=c; else ab[0]=c; }
      __syncthreads();
      a=ab[0]; b=ab[1];
      // renormalize on [a,b)
      double nn=0; for (int t=a+tid;t<b;t+=256) nn+=v[t]*v[t];
      red[tid]=nn; __syncthreads();
      for (int off=128;off;off>>=1){ if(tid<off) red[tid]+=red[tid+off]; __syncthreads(); }
      double inv = 1.0/sqrt(red[0]); __syncthreads();
      for (int t=a+tid;t<b;t+=256) v[t]*=inv;
      __syncthreads();
      // 2x inverse iteration within sub-block
      for (int it=0; it<2; it++){
        for (int t=a+tid;t<b;t+=256){
          int L=t-a;
          dd[L]=alphaH[t]-lam_s;
          if (t<b-1){ du[L]=betaH[t]; dl[L]=betaH[t]; }
          xx[L]=v[t];
        }
        __syncthreads();
        if (tid==0) gtsv_serial(b-a, dl, dd, du, xx);
        __syncthreads();
        double s2=0; for (int t=a+tid;t<b;t+=256){ double q=xx[t-a]; s2+=q*q; }
        red[tid]=s2; __syncthreads();
        for (int off=128;off;off>>=1){ if(tid<off) red[tid]+=red[tid+off]; __syncthreads(); }
        double inv2 = 1.0/sqrt(red[0]); __syncthreads();
        for (int t=a+tid;t<b;t+=256) v[t]=xx[t-a]*inv2;
        __syncthreads();
      }
      // Rayleigh quotient on sub-block
      double rq=0;
      for (int t=a+tid;t<b;t+=256){
        double s = alphaH[t]*v[t];
        if (t>a)   s += betaH[t-1]*v[t-1];
        if (t<b-1) s += betaH[t]*v[t+1];
        rq += v[t]*s;
      }
      red[tid]=rq; __syncthreads();
      for (int off=128;off;off>>=1){ if(tid<off) red[tid]+=red[tid+off]; __syncthreads(); }
      if (tid==0) lam_s=red[0];
      __syncthreads();
      continue;
    }
    // ACTIVE level: exact secular orientation invariant
    if (tid==0){
      double vc1 = v[c-1], vc = v[c];
      if (fabs(vc1) >= fabs(vc)){
        sig = (vc1 < 0.0) ? 1.f : -1.f;              // require v[c-1] < 0
      } else {
        double req = (betaH[c-1] >= 0.0) ? -1.0 : 1.0; // require sign(v[c]) = -sign(E)
        double have = (vc >= 0.0) ? 1.0 : -1.0;
        sig = (have == req) ? 1.f : -1.f;
      }
    }
    break;
  }
  __syncthreads();
  if (tid==0) sgnv[i]=sig;
}

// ---- m_i = Q v_i (descending reflectors), apply sigma, store E50[t][i] ----
__global__ void __launch_bounds__(256) k_applyQm(const double* __restrict__ Vh,
                                                 const double* __restrict__ tauv,
                                                 const double* __restrict__ V50,
                                                 const float* __restrict__ sgnv,
                                                 float* __restrict__ E50){
  __shared__ double u[1000];
  __shared__ double red[256];
  __shared__ double bc[1];
  int i = blockIdx.x, tid = threadIdx.x;
  for (int t=tid;t<1000;t+=256) u[t] = V50[(size_t)i*1000+t];
  __syncthreads();
  for (int k=997;k>=0;k--){
    const double* v = Vh + (size_t)k*MF;
    double a=0;
    for (int j=k+1+tid;j<1000;j+=256) a += v[j]*u[j];
    red[tid]=a; __syncthreads();
    for (int off=128;off;off>>=1){
      if (tid<off) red[tid]+=red[tid+off];
      __syncthreads();
    }
    if (tid==0) bc[0] = tauv[k]*red[0];
    __syncthreads();
    double td = bc[0];
    for (int j=k+1+tid;j<1000;j+=256) u[j] -= td*v[j];
    __syncthreads();
  }
  double s = (double)sgnv[i];
  for (int t=tid;t<1000;t+=256) E50[(size_t)t*NCOMP + i] = (float)(u[t]*s);
}

// ---------------- P = (x-mean) * E -> d_out pca region ----------------
__global__ void k_pca(const float* __restrict__ x, const float* __restrict__ mean,
                      const float* __restrict__ E, float* __restrict__ P){
  __shared__ float As[64][65];
  __shared__ float Es[64][65];
  int r0 = blockIdx.x*64;
  int tx = threadIdx.x & 15, ty = threadIdx.x >> 4;
  float acc[4][4];
  #pragma unroll
  for (int u=0;u<4;u++)
    #pragma unroll
    for (int v=0;v<4;v++) acc[u][v]=0.f;
  for (int k0=0;k0<MF;k0+=64){
    for (int t=threadIdx.x;t<64*64;t+=256){
      int i=t>>6, kk=t&63; int k=k0+kk;
      As[i][kk] = (k<MF) ? (x[(size_t)(r0+i)*MF+k]-mean[k]) : 0.f;
    }
    for (int t=threadIdx.x;t<64*65;t+=256){
      int kk=t/65, c=t%65; int k=k0+kk;
      Es[kk][c] = (k<MF && c<NCOMP) ? E[(size_t)k*NCOMP+c] : 0.f;
    }
    __syncthreads();
    for (int kk=0;kk<64;kk++){
      float a[4], b[4];
      #pragma unroll
      for (int u=0;u<4;u++){ a[u]=As[ty*4+u][kk]; b[u]=Es[kk][tx*4+u]; }
      #pragma unroll
      for (int u=0;u<4;u++)
        #pragma unroll
        for (int v=0;v<4;v++) acc[u][v] += a[u]*b[v];
    }
    __syncthreads();
  }
  #pragma unroll
  for (int u=0;u<4;u++){
    int r=r0+ty*4+u;
    #pragma unroll
    for (int v=0;v<4;v++){
      int c=tx*4+v;
      if (c<NCOMP) P[(size_t)r*NCOMP+c] = acc[u][v];
    }
  }
}

// ---------------- row squared norms ----------------
__global__ void k_rowsq(const float* __restrict__ P, float* __restrict__ sqv){
  int r = blockIdx.x*256 + threadIdx.x;
  if (r < NS){
    float s=0;
    for (int c=0;c<NCOMP;c++){ float v=P[(size_t)r*NCOMP+c]; s+=v*v; }
    sqv[r]=s;
  }
}

// ---------------- fused d2 + top-15 + transition row + diff weights ----------------
__global__ void k_knn(const float* __restrict__ P, const float* __restrict__ sqv,
                      float* __restrict__ trans, int* __restrict__ kidx,
                      float* __restrict__ kwd){
  __shared__ float pi[64];
  __shared__ unsigned long long keys[16*256];
  __shared__ unsigned long long red[256];
  __shared__ unsigned long long wink[15];
  __shared__ float wt[15], wd[15], sums[2];
  int i = blockIdx.x, tid = threadIdx.x;
  for (int t=tid;t<NCOMP;t+=256) pi[t] = P[(size_t)i*NCOMP+t];
  __syncthreads();
  float sqi = sqv[i];
  for (int s2=0;s2<16;s2++){
    int j = tid + s2*256;
    float dot=0;
    for (int c=0;c<NCOMP;c++) dot += pi[c]*P[(size_t)j*NCOMP+c];
    float d2 = sqi + sqv[j] - 2.f*dot;
    d2 = fmaxf(d2, 0.f);
    unsigned int db = __float_as_uint(d2);
    keys[s2*256+tid] = ((unsigned long long)db<<32) | (unsigned)j;
  }
  __syncthreads();
  for (int rsel=0;rsel<15;rsel++){
    unsigned long long m = ~0ull;
    for (int s2=0;s2<16;s2++){
      unsigned long long k = keys[s2*256+tid];
      m = (k<m)?k:m;
    }
    red[tid]=m; __syncthreads();
    for (int off=128;off>0;off>>=1){
      if (tid<off){ unsigned long long o=red[tid+off]; if (o<red[tid]) red[tid]=o; }
      __syncthreads();
    }
    unsigned long long w = red[0];
    if (tid==0) wink[rsel]=w;
    for (int s2=0;s2<16;s2++)
      if (keys[s2*256+tid]==w) keys[s2*256+tid]=~0ull;
    __syncthreads();
  }
  if (tid<15){
    unsigned long long w = wink[tid];
    float d2 = __uint_as_float((unsigned)(w>>32));
    wt[tid] = expf(-0.5f*d2);
    wd[tid] = expf(-d2);
  }
  __syncthreads();
  if (tid==0){
    float st=0, sd=0;
    for (int k=0;k<15;k++){ st+=wt[k]; sd+=wd[k]; }
    sums[0]=st; sums[1]=sd;
  }
  __syncthreads();
  float* row = trans + (size_t)i*NS;
  for (int c=tid;c<NS;c+=256) row[c]=0.f;
  __syncthreads();
  if (tid<15){
    int j = (int)(wink[tid] & 0xffffffffull);
    row[j] = wt[tid]/sums[0];
    kidx[i*15+tid] = j;
    kwd[i*15+tid]  = wd[tid]/sums[1];
  }
}

// ---------------- 100-iteration sparse power iteration ----------------
__global__ void __launch_bounds__(1024) k_power(const int* __restrict__ kidx,
                                                const float* __restrict__ kwd,
                                                float* __restrict__ outPT){
  __shared__ float d[4096];
  __shared__ float dn[4096];
  __shared__ float red[1024];
  int tid = threadIdx.x;
  for (int t=tid;t<4096;t+=1024) d[t] = (t==0)?1.f:0.f;
  __syncthreads();
  for (int it=0; it<100; it++){
    float lmax = 0.f;
    for (int r=tid;r<4096;r+=1024){
      float a=0;
      #pragma unroll
      for (int k=0;k<15;k++) a += kwd[r*15+k]*d[kidx[r*15+k]];
      dn[r]=a;
      lmax = fmaxf(lmax, a);
    }
    red[tid]=lmax; __syncthreads();
    for (int off=512;off>0;off>>=1){
      if (tid<off) red[tid]=fmaxf(red[tid], red[tid+off]);
      __syncthreads();
    }
    float m = red[0];
    for (int r=tid;r<4096;r+=1024) d[r]=dn[r]/m;
    __syncthreads();
  }
  for (int t=tid;t<4096;t+=1024) outPT[t]=d[t];
}

// ---------------- host ----------------
// Footprint ~16.9 MB (< 22.42 MB proven). Ah dies after k_hh_extract;
// sqv/kidx/kwd overlay it (used only in the final output phase).
extern "C" void kernel_launch(void* const* d_in, const int* in_sizes, int n_in,
                              void* d_out, int out_size, void* d_ws, size_t ws_size,
                              hipStream_t stream){
  const float* x = (const float*)d_in[0];
  float* out = (float*)d_out;
  char* base = (char*)d_ws;

  double* Ah     = (double*)(base + 0);            // 8,000,000 (dead after extract)
  float*  sqv    = (float*) (base + 0);            //    16,384 overlay
  int*    kidx   = (int*)   (base + 16384);        //   245,760 overlay
  float*  kwd    = (float*) (base + 262144);       //   245,760 overlay (ends 507,904)
  double* Vh     = (double*)(base + 8000000);      // 8,000,000
  double* V50    = (double*)(base + 16000000);     //   400,000
  float*  E50    = (float*) (base + 16400000);     //   200,000
  float*  part   = (float*) (base + 16600000);     //   256,000
  float*  mean   = (float*) (base + 16856000);     //     4,000
  double* tauv   = (double*)(base + 16860000);     //     8,000
  double* betaH  = (double*)(base + 16868000);     //     8,000
  double* alphaH = (double*)(base + 16876000);     //     8,000
  double* w1     = (double*)(base + 16884000);     //     8,000
  double* lamT   = (double*)(base + 16892000);     //       400
  double* lamR   = (double*)(base + 16892400);     //       400
  float*  sgnv   = (float*) (base + 16892800);     //       200

  k_colsum<<<64,256,0,stream>>>(x, part);
  k_colmean<<<4,256,0,stream>>>(part, mean);
  k_cov<<<dim3(16,16),dim3(16,16),0,stream>>>(x, mean, Ah);

  // fp64 Householder tridiagonalization (dsytd2 'L' conventions)
  for (int k=0;k<998;k++){
    k_hh_reflect<<<1,256,0,stream>>>(Ah, Vh, tauv, betaH, k);
    k_hh_symv   <<<128,256,0,stream>>>(Ah, Vh, w1, k);
    k_hh_rank2  <<<240,256,0,stream>>>(Ah, Vh, w1, tauv, k);
  }
  k_hh_extract<<<4,256,0,stream>>>(Ah, alphaH, betaH);

  // top-50 eigenpairs of T in fp64
  k_bisect<<<1,64,0,stream>>>(alphaH, betaH, lamT);
  k_inviter<<<50,256,0,stream>>>(alphaH, betaH, lamT, V50, lamR);

  // LAPACK D&C sign replication: last-active merge level + secular invariant
  k_sign<<<50,256,0,stream>>>(alphaH, betaH, V50, lamR, sgnv);

  // back-transform + sign -> eigenvector matrix, then outputs
  k_applyQm<<<50,256,0,stream>>>(Vh, tauv, V50, sgnv, E50);
  k_pca<<<64,256,0,stream>>>(x, mean, E50, out + PCA_OFF);
  k_rowsq<<<16,256,0,stream>>>(out + PCA_OFF, sqv);
  k_knn<<<4096,256,0,stream>>>(out + PCA_OFF, sqv, out + TR_OFF, kidx, kwd);
  k_power<<<1,1024,0,stream>>>(kidx, kwd, out);
}

// Round 10
// 19883.385 us; speedup vs baseline: 1.4511x; 1.4511x over previous
//
#include <hip/hip_runtime.h>
#include <math.h>
#include <stdint.h>

// ---- problem constants ----
static const int NS = 4096;    // samples
static const int MF = 1000;    // features
static const int NCOMP = 50;   // principal components

// out layout: pseudotime [4096] | transition [4096*4096] | pca [4096*50]
#define TR_OFF  ((size_t)4096)
#define PCA_OFF ((size_t)4096 + (size_t)4096*4096)

// ---------------- column mean ----------------
__global__ void k_colsum(const float* __restrict__ x, float* __restrict__ part){
  int b = blockIdx.x, tid = threadIdx.x;
  float a0=0,a1=0,a2=0,a3=0;
  for (int r=b*64; r<b*64+64; r++){
    const float* row = x + (size_t)r*MF;
    if (tid      < MF) a0 += row[tid];
    if (tid+256  < MF) a1 += row[tid+256];
    if (tid+512  < MF) a2 += row[tid+512];
    if (tid+768  < MF) a3 += row[tid+768];
  }
  if (tid      < MF) part[b*MF+tid]     = a0;
  if (tid+256  < MF) part[b*MF+tid+256] = a1;
  if (tid+512  < MF) part[b*MF+tid+512] = a2;
  if (tid+768  < MF) part[b*MF+tid+768] = a3;
}

__global__ void k_colmean(const float* __restrict__ part, float* __restrict__ mean){
  int c = blockIdx.x*256 + threadIdx.x;
  if (c < MF){ float s=0; for (int b=0;b<64;b++) s += part[b*MF+c]; mean[c] = s/4096.0f; }
}

// ---------------- cov = (x-mean)^T (x-mean) / (n-1), fp64 out ----------------
__global__ void k_cov(const float* __restrict__ x, const float* __restrict__ mean,
                      double* __restrict__ Ah){
  __shared__ float As[32][65];
  __shared__ float Bs[32][65];
  int i0 = blockIdx.y*64, j0 = blockIdx.x*64;
  int tx = threadIdx.x, ty = threadIdx.y;
  int tid = ty*16+tx;
  double acc[4][4];
  #pragma unroll
  for (int u=0;u<4;u++)
    #pragma unroll
    for (int v=0;v<4;v++) acc[u][v]=0.0;
  for (int k0=0;k0<4096;k0+=32){
    for (int t=tid;t<32*64;t+=256){
      int kk=t>>6, ii=t&63;
      int gi=i0+ii, gj=j0+ii;
      As[kk][ii] = (gi<MF) ? (x[(size_t)(k0+kk)*MF+gi]-mean[gi]) : 0.f;
      Bs[kk][ii] = (gj<MF) ? (x[(size_t)(k0+kk)*MF+gj]-mean[gj]) : 0.f;
    }
    __syncthreads();
    for (int kk=0;kk<32;kk++){
      float a[4], b[4];
      #pragma unroll
      for (int u=0;u<4;u++){ a[u]=As[kk][ty*4+u]; b[u]=Bs[kk][tx*4+u]; }
      #pragma unroll
      for (int u=0;u<4;u++)
        #pragma unroll
        for (int v=0;v<4;v++) acc[u][v] += (double)a[u]*(double)b[v];
    }
    __syncthreads();
  }
  #pragma unroll
  for (int u=0;u<4;u++)
    #pragma unroll
    for (int v=0;v<4;v++){
      int gi=i0+ty*4+u, gj=j0+tx*4+v;
      if (gi<MF && gj<MF) Ah[(size_t)gi*MF+gj] = acc[u][v]*(1.0/4095.0);
    }
}

__device__ __forceinline__ unsigned wang(unsigned s){
  s=(s^61u)^(s>>16); s*=9u; s^=s>>4; s*=0x27d4eb2du; s^=s>>15; return s;
}

// ======== FUSED fp64 Householder step (dsytd2 'L', lazy rank-2 apply) ========
// Kernel k: (1) rebuild updated column k from staged colprev + analytic rank-2
// correction of step k-1 -> reflector v_k (dlarfg, LAPACK signs), (2) row pass:
// apply update k-1 to rows r>=k+1 (cols>=k+1), fused symv acc w1_k[r] = A_upd v_k,
// stage column k+1 into colnext. Expression-identical arithmetic to the unfused
// version (a - (vr*wc + wr*vc)), so the fp64 trajectory matches to ~ulp.
__global__ void __launch_bounds__(256) k_hh_step(double* __restrict__ Ah,
                                                 double* __restrict__ Vh,
                                                 double* __restrict__ tauv,
                                                 double* __restrict__ betaH,
                                                 const double* __restrict__ w1prev,
                                                 double* __restrict__ w1next,
                                                 const double* __restrict__ colprev,
                                                 double* __restrict__ colnext,
                                                 int k){
  __shared__ double vprev[1000], wfull[1000], vk[1000];
  __shared__ double red[256];
  __shared__ double sc[1];
  int tid = threadIdx.x;

  // ---- prologue: load v_{k-1}, w1_{k-1}; vdot; wfull = tau*w1 - hts*v ----
  double vd = 0;
  if (k > 0){
    for (int j = k + tid; j < 1000; j += 256){
      double vv = Vh[(size_t)(k-1)*MF + j];
      double ww = w1prev[j];
      vprev[j] = vv;
      wfull[j] = ww;
      vd += vv*ww;
    }
  }
  red[tid] = vd; __syncthreads();
  for (int off=128; off; off>>=1){ if (tid<off) red[tid]+=red[tid+off]; __syncthreads(); }
  double vdot = red[0];
  double tp = (k>0) ? tauv[k-1] : 0.0;
  double hts = 0.5*tp*tp*vdot;
  __syncthreads();
  if (k > 0){
    for (int j = k + tid; j < 1000; j += 256)
      wfull[j] = tp*wfull[j] - hts*vprev[j];
  }
  __syncthreads();

  // ---- updated column k (into vk[]), alpha & tail norm ----
  double a2 = 0;
  for (int j = k+1 + tid; j < 1000; j += 256){
    double c;
    if (k > 0) c = colprev[j] - (vprev[j]*wfull[k] + wfull[j]*vprev[k]);
    else       c = Ah[(size_t)j*MF + k];
    vk[j] = c;
    if (j > k+1) a2 += c*c;
  }
  red[tid]=a2; __syncthreads();
  for (int off=128; off; off>>=1){ if (tid<off) red[tid]+=red[tid+off]; __syncthreads(); }
  if (tid==0){
    double alpha = vk[k+1];
    double xn2 = red[0];
    double beta, tau, scl;
    if (xn2 == 0.0){ beta = alpha; tau = 0.0; scl = 0.0; }
    else {
      double nrm = sqrt(alpha*alpha + xn2);
      beta = (alpha >= 0.0) ? -nrm : nrm;   // dlarfg: beta = -sign(alpha)*norm
      tau  = (beta - alpha)/beta;
      scl  = 1.0/(alpha - beta);
    }
    sc[0]=scl;
    if (blockIdx.x==0){
      tauv[k]=tau; betaH[k]=beta;
      if (k>0) Ah[(size_t)k*MF + k] -= 2.0*wfull[k];   // row-k diagonal, last touch
    }
  }
  __syncthreads();
  double scl = sc[0];
  for (int j = k+1 + tid; j < 1000; j += 256)
    vk[j] = (j == k+1) ? 1.0 : vk[j]*scl;
  __syncthreads();
  if (blockIdx.x==0){
    for (int j = k+1 + tid; j < 1000; j += 256)
      Vh[(size_t)k*MF + j] = vk[j];
  }

  // ---- row pass: update k-1 + fused symv + stage column k+1 ----
  for (int r = k+1 + blockIdx.x; r < 1000; r += gridDim.x){
    double vr = (k>0)? vprev[r] : 0.0;
    double wr = (k>0)? wfull[r] : 0.0;
    double* row = Ah + (size_t)r*MF;
    double acc = 0;
    for (int c = k+1 + tid; c < 1000; c += 256){
      double a = row[c];
      if (k > 0){
        a -= vr*wfull[c] + wr*vprev[c];
        row[c] = a;
      }
      acc += a*vk[c];
      if (c == k+1) colnext[r] = a;
    }
    // wave-shuffle reduce (4 waves)
    for (int off=32; off; off>>=1) acc += __shfl_down(acc, off, 64);
    if ((tid & 63)==0) red[tid>>6] = acc;
    __syncthreads();
    if (tid==0) w1next[r] = red[0]+red[1]+red[2]+red[3];
    __syncthreads();
  }
}

// apply pending update 997 to trailing 2x2 (single thread)
__global__ void k_hh_fin(double* __restrict__ Ah, const double* __restrict__ Vh,
                         const double* __restrict__ tauv,
                         const double* __restrict__ w1last){
  if (threadIdx.x==0 && blockIdx.x==0){
    double v8 = Vh[(size_t)997*MF + 998];   // == 1.0
    double v9 = Vh[(size_t)997*MF + 999];
    double w18 = w1last[998], w19 = w1last[999];
    double tau = tauv[997];
    double vdot = v8*w18 + v9*w19;
    double hts = 0.5*tau*tau*vdot;
    double w8 = tau*w18 - hts*v8;
    double w9 = tau*w19 - hts*v9;
    Ah[(size_t)998*MF+998] -= v8*w8 + w8*v8;
    Ah[(size_t)999*MF+998] -= v9*w8 + w9*v8;
    Ah[(size_t)999*MF+999] -= v9*w9 + w9*v9;
  }
}

__global__ void k_hh_extract(const double* __restrict__ Ah, double* __restrict__ alphaH,
                             double* __restrict__ betaH){
  int t = blockIdx.x*256 + threadIdx.x;
  if (t < MF) alphaH[t] = Ah[(size_t)t*MF+t];
  if (t == 0) betaH[998] = Ah[(size_t)999*MF+998];
}

// ---- Sturm bisection: top-50 eigenvalues of T ----
__global__ void k_bisect(const double* __restrict__ alphaT, const double* __restrict__ betaT,
                         double* __restrict__ lamT){
  int i = blockIdx.x*blockDim.x + threadIdx.x;
  if (i >= NCOMP) return;
  double lo=1e300, hi=-1e300;
  for (int k=0;k<1000;k++){
    double bl = (k>0)? fabs(betaT[k-1]) : 0.0;
    double br = (k<999)? fabs(betaT[k]) : 0.0;
    double a = alphaT[k];
    lo = fmin(lo, a-bl-br);
    hi = fmax(hi, a+bl+br);
  }
  int target = 999 - i;
  for (int it=0; it<55; it++){
    double mid = 0.5*(lo+hi);
    int cnt=0;
    double d = alphaT[0]-mid;
    if (d<0.0) cnt++;
    for (int k=1;k<1000;k++){
      double b = betaT[k-1];
      double den = d;
      if (fabs(den) < 1e-300) den = (den<0.0)?-1e-300:1e-300;
      d = alphaT[k]-mid - b*b/den;
      if (d<0.0) cnt++;
    }
    if (cnt > target) hi = mid; else lo = mid;
  }
  lamT[i] = 0.5*(lo+hi);
}

// ---- serial pivoted tridiagonal solve (LAPACK dgtsv replica), thread-0 only ----
__device__ void gtsv_serial(int m, double* dl, double* dd, double* du, double* x){
  for (int r=0;r<m-1;r++){
    if (fabs(dd[r]) >= fabs(dl[r])){
      if (dd[r] != 0.0){
        double fact = dl[r]/dd[r];
        dd[r+1] -= fact*du[r];
        x[r+1]  -= fact*x[r];
      }
      if (r < m-2) dl[r] = 0.0;
    } else {
      double fact = dd[r]/dl[r];
      dd[r] = dl[r];
      double tdd = dd[r+1];
      dd[r+1] = du[r] - fact*tdd;
      if (r < m-2){
        double tdu = du[r+1];
        dl[r] = tdu;
        du[r+1] = -fact*tdu;
      }
      du[r] = tdd;
      double t2 = x[r]; x[r] = x[r+1]; x[r+1] = t2 - fact*x[r+1];
    }
  }
  x[m-1] /= dd[m-1];
  if (m >= 2) x[m-2] = (x[m-2] - du[m-2]*x[m-1])/dd[m-2];
  for (int r=m-3;r>=0;r--)
    x[r] = (x[r] - du[r]*x[r+1] - dl[r]*x[r+2])/dd[r];
}

// ---- inverse iteration on full T: fp64 eigenvector + refined lambda ----
__global__ void __launch_bounds__(256) k_inviter(const double* __restrict__ alphaH,
                                                 const double* __restrict__ betaH,
                                                 const double* __restrict__ lamT,
                                                 double* __restrict__ V50,
                                                 double* __restrict__ lamR){
  __shared__ double v[1000], xx[1000], dd[1000], du[1000], dl[1000];
  __shared__ double red[256];
  int i = blockIdx.x, tid = threadIdx.x;
  double lam = lamT[i];
  for (int t=tid;t<1000;t+=256){
    unsigned h = wang((unsigned)(i*1000+t)*2654435761u + 777u);
    v[t] = (double)(h & 0xffffffu)/8388608.0 - 1.0;
  }
  __syncthreads();
  for (int it=0; it<3; it++){
    for (int t=tid;t<1000;t+=256){
      dd[t] = alphaH[t]-lam;
      if (t<999){ du[t]=betaH[t]; dl[t]=betaH[t]; }
      xx[t] = v[t];
    }
    __syncthreads();
    if (tid==0) gtsv_serial(1000, dl, dd, du, xx);
    __syncthreads();
    double a=0; for (int t=tid;t<1000;t+=256) a += xx[t]*xx[t];
    red[tid]=a; __syncthreads();
    for (int off=128;off;off>>=1){ if(tid<off) red[tid]+=red[tid+off]; __syncthreads(); }
    double inv = 1.0/sqrt(red[0]);
    __syncthreads();
    for (int t=tid;t<1000;t+=256) v[t]=xx[t]*inv;
    __syncthreads();
  }
  double a=0;
  for (int t=tid;t<1000;t+=256){
    double s = alphaH[t]*v[t];
    if (t>0)   s += betaH[t-1]*v[t-1];
    if (t<999) s += betaH[t]*v[t+1];
    a += v[t]*s;
  }
  red[tid]=a; __syncthreads();
  for (int off=128;off;off>>=1){ if(tid<off) red[tid]+=red[tid+off]; __syncthreads(); }
  if (tid==0) lamR[i]=red[0];
  for (int t=tid;t<1000;t+=256) V50[(size_t)i*1000+t]=v[t];
}

// ---- LAPACK D&C sign replication: last-active merge level + secular invariant ----
__global__ void __launch_bounds__(256) k_sign(const double* __restrict__ alphaH,
                                              const double* __restrict__ betaH,
                                              const double* __restrict__ V50,
                                              const double* __restrict__ lamR,
                                              float* __restrict__ sgnv){
  __shared__ double v[1000], xx[1000], dd[1000], du[1000], dl[1000];
  __shared__ double red[256];
  __shared__ double lam_s;
  __shared__ int ab[2];
  __shared__ float sig;
  int i = blockIdx.x, tid = threadIdx.x;
  for (int t=tid;t<1000;t+=256) v[t]=V50[(size_t)i*1000+t];
  if (tid==0){ lam_s=lamR[i]; ab[0]=0; ab[1]=1000; sig=1.f; }
  __syncthreads();
  while (true){
    int a=ab[0], b=ab[1];
    if (b-a <= 25) break;
    int c = a + (b-a)/2;
    double m1=0,m2=0;
    for (int t=a+tid;t<b;t+=256){ double q=v[t]*v[t]; if (t<c) m1+=q; else m2+=q; }
    red[tid]=m1; __syncthreads();
    for (int off=128;off;off>>=1){ if(tid<off) red[tid]+=red[tid+off]; __syncthreads(); }
    double M1=red[0]; __syncthreads();
    red[tid]=m2; __syncthreads();
    for (int off=128;off;off>>=1){ if(tid<off) red[tid]+=red[tid+off]; __syncthreads(); }
    double M2=red[0]; __syncthreads();
    double tot=M1+M2;
    if (fmin(M1,M2) <= 1e-10*tot){
      if (tid==0){ if (M1>=M2) ab[1]=c; else ab[0]=c; }
      __syncthreads();
      a=ab[0]; b=ab[1];
      double nn=0; for (int t=a+tid;t<b;t+=256) nn+=v[t]*v[t];
      red[tid]=nn; __syncthreads();
      for (int off=128;off;off>>=1){ if(tid<off) red[tid]+=red[tid+off]; __syncthreads(); }
      double inv = 1.0/sqrt(red[0]); __syncthreads();
      for (int t=a+tid;t<b;t+=256) v[t]*=inv;
      __syncthreads();
      for (int it=0; it<2; it++){
        for (int t=a+tid;t<b;t+=256){
          int L=t-a;
          dd[L]=alphaH[t]-lam_s;
          if (t<b-1){ du[L]=betaH[t]; dl[L]=betaH[t]; }
          xx[L]=v[t];
        }
        __syncthreads();
        if (tid==0) gtsv_serial(b-a, dl, dd, du, xx);
        __syncthreads();
        double s2=0; for (int t=a+tid;t<b;t+=256){ double q=xx[t-a]; s2+=q*q; }
        red[tid]=s2; __syncthreads();
        for (int off=128;off;off>>=1){ if(tid<off) red[tid]+=red[tid+off]; __syncthreads(); }
        double inv2 = 1.0/sqrt(red[0]); __syncthreads();
        for (int t=a+tid;t<b;t+=256) v[t]=xx[t-a]*inv2;
        __syncthreads();
      }
      double rq=0;
      for (int t=a+tid;t<b;t+=256){
        double s = alphaH[t]*v[t];
        if (t>a)   s += betaH[t-1]*v[t-1];
        if (t<b-1) s += betaH[t]*v[t+1];
        rq += v[t]*s;
      }
      red[tid]=rq; __syncthreads();
      for (int off=128;off;off>>=1){ if(tid<off) red[tid]+=red[tid+off]; __syncthreads(); }
      if (tid==0) lam_s=red[0];
      __syncthreads();
      continue;
    }
    if (tid==0){
      double vc1 = v[c-1], vc = v[c];
      if (fabs(vc1) >= fabs(vc)){
        sig = (vc1 < 0.0) ? 1.f : -1.f;
      } else {
        double req = (betaH[c-1] >= 0.0) ? -1.0 : 1.0;
        double have = (vc >= 0.0) ? 1.0 : -1.0;
        sig = (have == req) ? 1.f : -1.f;
      }
    }
    break;
  }
  __syncthreads();
  if (tid==0) sgnv[i]=sig;
}

// ---- m_i = Q v_i (descending reflectors), apply sigma, store E50[t][i] ----
__global__ void __launch_bounds__(256) k_applyQm(const double* __restrict__ Vh,
                                                 const double* __restrict__ tauv,
                                                 const double* __restrict__ V50,
                                                 const float* __restrict__ sgnv,
                                                 float* __restrict__ E50){
  __shared__ double u[1000];
  __shared__ double red[256];
  __shared__ double bc[1];
  int i = blockIdx.x, tid = threadIdx.x;
  for (int t=tid;t<1000;t+=256) u[t] = V50[(size_t)i*1000+t];
  __syncthreads();
  for (int k=997;k>=0;k--){
    const double* v = Vh + (size_t)k*MF;
    double a=0;
    for (int j=k+1+tid;j<1000;j+=256) a += v[j]*u[j];
    red[tid]=a; __syncthreads();
    for (int off=128;off;off>>=1){
      if (tid<off) red[tid]+=red[tid+off];
      __syncthreads();
    }
    if (tid==0) bc[0] = tauv[k]*red[0];
    __syncthreads();
    double td = bc[0];
    for (int j=k+1+tid;j<1000;j+=256) u[j] -= td*v[j];
    __syncthreads();
  }
  double s = (double)sgnv[i];
  for (int t=tid;t<1000;t+=256) E50[(size_t)t*NCOMP + i] = (float)(u[t]*s);
}

// ---------------- P = (x-mean) * E -> d_out pca region ----------------
__global__ void k_pca(const float* __restrict__ x, const float* __restrict__ mean,
                      const float* __restrict__ E, float* __restrict__ P){
  __shared__ float As[64][65];
  __shared__ float Es[64][65];
  int r0 = blockIdx.x*64;
  int tx = threadIdx.x & 15, ty = threadIdx.x >> 4;
  float acc[4][4];
  #pragma unroll
  for (int u=0;u<4;u++)
    #pragma unroll
    for (int v=0;v<4;v++) acc[u][v]=0.f;
  for (int k0=0;k0<MF;k0+=64){
    for (int t=threadIdx.x;t<64*64;t+=256){
      int i=t>>6, kk=t&63; int k=k0+kk;
      As[i][kk] = (k<MF) ? (x[(size_t)(r0+i)*MF+k]-mean[k]) : 0.f;
    }
    for (int t=threadIdx.x;t<64*65;t+=256){
      int kk=t/65, c=t%65; int k=k0+kk;
      Es[kk][c] = (k<MF && c<NCOMP) ? E[(size_t)k*NCOMP+c] : 0.f;
    }
    __syncthreads();
    for (int kk=0;kk<64;kk++){
      float a[4], b[4];
      #pragma unroll
      for (int u=0;u<4;u++){ a[u]=As[ty*4+u][kk]; b[u]=Es[kk][tx*4+u]; }
      #pragma unroll
      for (int u=0;u<4;u++)
        #pragma unroll
        for (int v=0;v<4;v++) acc[u][v] += a[u]*b[v];
    }
    __syncthreads();
  }
  #pragma unroll
  for (int u=0;u<4;u++){
    int r=r0+ty*4+u;
    #pragma unroll
    for (int v=0;v<4;v++){
      int c=tx*4+v;
      if (c<NCOMP) P[(size_t)r*NCOMP+c] = acc[u][v];
    }
  }
}

// ---------------- row squared norms ----------------
__global__ void k_rowsq(const float* __restrict__ P, float* __restrict__ sqv){
  int r = blockIdx.x*256 + threadIdx.x;
  if (r < NS){
    float s=0;
    for (int c=0;c<NCOMP;c++){ float v=P[(size_t)r*NCOMP+c]; s+=v*v; }
    sqv[r]=s;
  }
}

// ---------------- fused d2 + top-15 + transition row + diff weights ----------------
__global__ void k_knn(const float* __restrict__ P, const float* __restrict__ sqv,
                      float* __restrict__ trans, int* __restrict__ kidx,
                      float* __restrict__ kwd){
  __shared__ float pi[64];
  __shared__ unsigned long long keys[16*256];
  __shared__ unsigned long long red[256];
  __shared__ unsigned long long wink[15];
  __shared__ float wt[15], wd[15], sums[2];
  int i = blockIdx.x, tid = threadIdx.x;
  for (int t=tid;t<NCOMP;t+=256) pi[t] = P[(size_t)i*NCOMP+t];
  __syncthreads();
  float sqi = sqv[i];
  for (int s2=0;s2<16;s2++){
    int j = tid + s2*256;
    float dot=0;
    for (int c=0;c<NCOMP;c++) dot += pi[c]*P[(size_t)j*NCOMP+c];
    float d2 = sqi + sqv[j] - 2.f*dot;
    d2 = fmaxf(d2, 0.f);
    unsigned int db = __float_as_uint(d2);
    keys[s2*256+tid] = ((unsigned long long)db<<32) | (unsigned)j;
  }
  __syncthreads();
  for (int rsel=0;rsel<15;rsel++){
    unsigned long long m = ~0ull;
    for (int s2=0;s2<16;s2++){
      unsigned long long k = keys[s2*256+tid];
      m = (k<m)?k:m;
    }
    red[tid]=m; __syncthreads();
    for (int off=128;off>0;off>>=1){
      if (tid<off){ unsigned long long o=red[tid+off]; if (o<red[tid]) red[tid]=o; }
      __syncthreads();
    }
    unsigned long long w = red[0];
    if (tid==0) wink[rsel]=w;
    for (int s2=0;s2<16;s2++)
      if (keys[s2*256+tid]==w) keys[s2*256+tid]=~0ull;
    __syncthreads();
  }
  if (tid<15){
    unsigned long long w = wink[tid];
    float d2 = __uint_as_float((unsigned)(w>>32));
    wt[tid] = expf(-0.5f*d2);
    wd[tid] = expf(-d2);
  }
  __syncthreads();
  if (tid==0){
    float st=0, sd=0;
    for (int k=0;k<15;k++){ st+=wt[k]; sd+=wd[k]; }
    sums[0]=st; sums[1]=sd;
  }
  __syncthreads();
  float* row = trans + (size_t)i*NS;
  for (int c=tid;c<NS;c+=256) row[c]=0.f;
  __syncthreads();
  if (tid<15){
    int j = (int)(wink[tid] & 0xffffffffull);
    row[j] = wt[tid]/sums[0];
    kidx[i*15+tid] = j;
    kwd[i*15+tid]  = wd[tid]/sums[1];
  }
}

// ---------------- 100-iteration sparse power iteration ----------------
__global__ void __launch_bounds__(1024) k_power(const int* __restrict__ kidx,
                                                const float* __restrict__ kwd,
                                                float* __restrict__ outPT){
  __shared__ float d[4096];
  __shared__ float dn[4096];
  __shared__ float red[1024];
  int tid = threadIdx.x;
  for (int t=tid;t<4096;t+=1024) d[t] = (t==0)?1.f:0.f;
  __syncthreads();
  for (int it=0; it<100; it++){
    float lmax = 0.f;
    for (int r=tid;r<4096;r+=1024){
      float a=0;
      #pragma unroll
      for (int k=0;k<15;k++) a += kwd[r*15+k]*d[kidx[r*15+k]];
      dn[r]=a;
      lmax = fmaxf(lmax, a);
    }
    red[tid]=lmax; __syncthreads();
    for (int off=512;off>0;off>>=1){
      if (tid<off) red[tid]=fmaxf(red[tid], red[tid+off]);
      __syncthreads();
    }
    float m = red[0];
    for (int r=tid;r<4096;r+=1024) d[r]=dn[r]/m;
    __syncthreads();
  }
  for (int t=tid;t<4096;t+=1024) outPT[t]=d[t];
}

// ---------------- host ----------------
// Footprint ~16.93 MB (< 22.42 MB proven). Ah dies after extract;
// sqv/kidx/kwd overlay it (used only in the final output phase).
extern "C" void kernel_launch(void* const* d_in, const int* in_sizes, int n_in,
                              void* d_out, int out_size, void* d_ws, size_t ws_size,
                              hipStream_t stream){
  const float* x = (const float*)d_in[0];
  float* out = (float*)d_out;
  char* base = (char*)d_ws;

  double* Ah     = (double*)(base + 0);            // 8,000,000 (dead after extract)
  float*  sqv    = (float*) (base + 0);            //    16,384 overlay
  int*    kidx   = (int*)   (base + 16384);        //   245,760 overlay
  float*  kwd    = (float*) (base + 262144);       //   245,760 overlay (ends 507,904)
  double* Vh     = (double*)(base + 8000000);      // 8,000,000
  double* V50    = (double*)(base + 16000000);     //   400,000
  float*  E50    = (float*) (base + 16400000);     //   200,000
  float*  part   = (float*) (base + 16600000);     //   256,000
  float*  mean   = (float*) (base + 16856000);     //     4,000
  double* tauv   = (double*)(base + 16860000);     //     8,000
  double* betaH  = (double*)(base + 16868000);     //     8,000
  double* alphaH = (double*)(base + 16876000);     //     8,000
  double* w1a    = (double*)(base + 16884000);     //     8,000
  double* w1b    = (double*)(base + 16892000);     //     8,000
  double* cola   = (double*)(base + 16900000);     //     8,000
  double* colb   = (double*)(base + 16908000);     //     8,000
  double* lamT   = (double*)(base + 16916000);     //       400
  double* lamR   = (double*)(base + 16916400);     //       400
  float*  sgnv   = (float*) (base + 16916800);     //       200

  double* w1buf[2]  = { w1a, w1b };
  double* colbuf[2] = { cola, colb };

  k_colsum<<<64,256,0,stream>>>(x, part);
  k_colmean<<<4,256,0,stream>>>(part, mean);
  k_cov<<<dim3(16,16),dim3(16,16),0,stream>>>(x, mean, Ah);

  // fused fp64 Householder tridiagonalization (dsytd2 'L', 1 kernel/step)
  for (int k=0;k<998;k++){
    int m = 999-k;
    int g = m < 240 ? m : 240;
    k_hh_step<<<g,256,0,stream>>>(Ah, Vh, tauv, betaH,
        w1buf[(k+1)&1], w1buf[k&1], colbuf[(k+1)&1], colbuf[k&1], k);
  }
  k_hh_fin<<<1,64,0,stream>>>(Ah, Vh, tauv, w1buf[997&1]);
  k_hh_extract<<<4,256,0,stream>>>(Ah, alphaH, betaH);

  // top-50 eigenpairs of T in fp64
  k_bisect<<<1,64,0,stream>>>(alphaH, betaH, lamT);
  k_inviter<<<50,256,0,stream>>>(alphaH, betaH, lamT, V50, lamR);

  // LAPACK D&C sign replication
  k_sign<<<50,256,0,stream>>>(alphaH, betaH, V50, lamR, sgnv);

  // back-transform + sign -> eigenvectors, then outputs
  k_applyQm<<<50,256,0,stream>>>(Vh, tauv, V50, sgnv, E50);
  k_pca<<<64,256,0,stream>>>(x, mean, E50, out + PCA_OFF);
  k_rowsq<<<16,256,0,stream>>>(out + PCA_OFF, sqv);
  k_knn<<<4096,256,0,stream>>>(out + PCA_OFF, sqv, out + TR_OFF, kidx, kwd);
  k_power<<<1,1024,0,stream>>>(kidx, kwd, out);
}